// Round 4
// baseline (84.012 us; speedup 1.0000x reference)
//
#include <hip/hip_runtime.h>
#include <math.h>

// Problem constants (fixed by setup_inputs): C=64, HW=128*128, bins=256.
#define C_CH  64
#define HW    16384
#define BINS  256

// Cross-block reduce state: module-static device globals, zero-initialized at
// module load. Self-resetting: the last (ticket) block restores both to 0
// after writing out[0], so every stream-serialized replay starts clean.
__device__ float    g_sse = 0.0f;
__device__ unsigned g_cnt = 0u;

__device__ inline float4 ld4(const float* p) { return *(const float4*)p; }

__device__ inline int lbound(const float* a, float rank) {
    int lo = 0, hi = BINS;
    while (lo < hi) { int mid = (lo + hi) >> 1; if (a[mid] < rank) lo = mid + 1; else hi = mid; }
    return (lo > 255) ? 255 : lo;   // defensive; a[255]=N>=rank
}

// ONE kernel, 64 blocks x 1024 threads: block = channel. No cross-block
// dependency except the final SSE sum: every block redundantly computes
// channel 0's histogram/cdf and ch0 input stats from raw data (128KB of
// L2/L3-hot redundant reads per block beats any grid barrier / extra launch).
// Phases: A) load all 5 streams once into regs, 7 fused min/max/sum
// reductions. B) two LDS histograms (zero-trick, no atomics for exact 0s).
// C) dual wave scan -> cdf_c, cdf_0; T LUT from cdf_0 + ch0 input stats.
// D) 16-consecutive-rank marching CDF inversion, SSE, ticket finale.
__global__ __launch_bounds__(1024) void fused_one(const float* __restrict__ input,
                                                  const float* __restrict__ match,
                                                  const float* __restrict__ mask,
                                                  float* __restrict__ out) {
    const int c = blockIdx.x, tid = threadIdx.x;
    const int wave = tid >> 6, lane = tid & 63;

    __shared__ int   hc[BINS], h0[BINS];
    __shared__ float scdf[BINS], sc0[BINS], sT[BINS];
    __shared__ float wr[7][16];

    const float* mc = match + c * HW;
    const float* xc = input + c * HW;
    const int e0 = 16 * tid;   // 16 consecutive elements per thread

    float vm[16], vm0[16], vx[16];
    float mn = INFINITY,  mx = -INFINITY;    // match_c * mask
    float mn0 = INFINITY, mx0 = -INFINITY;   // match_0 * mask
    float xmn = INFINITY, xmx = -INFINITY;   // input_0 * mask (T-LUT stats)
    float ms = 0.0f;                         // mask sum (0/1 values: exact)

    // ---------------- phase A: all global loads, once ----------------
    #pragma unroll
    for (int k = 0; k < 4; k++) {
        float4 kv4 = ld4(mask  + e0 + 4 * k);
        float4 a4  = ld4(mc    + e0 + 4 * k);
        float4 b4  = ld4(match + e0 + 4 * k);   // channel 0
        float4 c4  = ld4(xc    + e0 + 4 * k);
        float4 d4  = ld4(input + e0 + 4 * k);   // channel 0
        float kk[4] = { kv4.x, kv4.y, kv4.z, kv4.w };
        float aa[4] = { a4.x, a4.y, a4.z, a4.w };
        float bb[4] = { b4.x, b4.y, b4.z, b4.w };
        float cc[4] = { c4.x, c4.y, c4.z, c4.w };
        float dd[4] = { d4.x, d4.y, d4.z, d4.w };
        #pragma unroll
        for (int j = 0; j < 4; j++) {
            float pm  = aa[j] * kk[j];
            float pm0 = bb[j] * kk[j];
            float px  = cc[j] * kk[j];
            float p0  = dd[j] * kk[j];
            vm [4*k+j] = pm;
            vm0[4*k+j] = pm0;
            vx [4*k+j] = px;
            mn  = fminf(mn,  pm);  mx  = fmaxf(mx,  pm);
            mn0 = fminf(mn0, pm0); mx0 = fmaxf(mx0, pm0);
            xmn = fminf(xmn, p0);  xmx = fmaxf(xmx, p0);
            ms += kk[j];
        }
    }
    #pragma unroll
    for (int s = 32; s > 0; s >>= 1) {
        mn  = fminf(mn,  __shfl_xor(mn,  s, 64));
        mx  = fmaxf(mx,  __shfl_xor(mx,  s, 64));
        mn0 = fminf(mn0, __shfl_xor(mn0, s, 64));
        mx0 = fmaxf(mx0, __shfl_xor(mx0, s, 64));
        xmn = fminf(xmn, __shfl_xor(xmn, s, 64));
        xmx = fmaxf(xmx, __shfl_xor(xmx, s, 64));
        ms += __shfl_xor(ms, s, 64);
    }
    if (lane == 0) {
        wr[0][wave] = mn;  wr[1][wave] = mx;
        wr[2][wave] = mn0; wr[3][wave] = mx0;
        wr[4][wave] = xmn; wr[5][wave] = xmx;
        wr[6][wave] = ms;
    }
    if (tid < BINS) { hc[tid] = 0; h0[tid] = 0; }
    __syncthreads();
    mn = wr[0][0]; mx = wr[1][0]; mn0 = wr[2][0]; mx0 = wr[3][0];
    xmn = wr[4][0]; xmx = wr[5][0]; ms = wr[6][0];
    #pragma unroll
    for (int j = 1; j < 16; j++) {
        mn  = fminf(mn,  wr[0][j]); mx  = fmaxf(mx,  wr[1][j]);
        mn0 = fminf(mn0, wr[2][j]); mx0 = fmaxf(mx0, wr[3][j]);
        xmn = fminf(xmn, wr[4][j]); xmx = fmaxf(xmx, wr[5][j]);
        ms += wr[6][j];
    }

    // torch.histc widths: w=(mx-mn)/bins; safe_w = w>0 ? w : 1  (/256 exact)
    float swc = (mx  - mn ) * (1.0f / 256.0f); swc = (swc > 0.0f) ? swc : 1.0f;
    float sw0 = (mx0 - mn0) * (1.0f / 256.0f); sw0 = (sw0 > 0.0f) ? sw0 : 1.0f;

    // ---------------- phase B: two histograms from registers ----------------
    int zc = 0, zc0 = 0;   // exact zeros (incl -0): counted without atomics
    #pragma unroll
    for (int j = 0; j < 16; j++) {
        if (vm[j] == 0.0f) { zc++; }
        else {
            float b = floorf((vm[j] - mn) / swc);
            b = fminf(fmaxf(b, 0.0f), 255.0f);   // clip in float like the ref
            atomicAdd(&hc[(int)b], 1);
        }
        if (vm0[j] == 0.0f) { zc0++; }
        else {
            float b = floorf((vm0[j] - mn0) / sw0);
            b = fminf(fmaxf(b, 0.0f), 255.0f);
            atomicAdd(&h0[(int)b], 1);
        }
    }
    #pragma unroll
    for (int s = 32; s > 0; s >>= 1) {
        zc  += __shfl_xor(zc,  s, 64);
        zc0 += __shfl_xor(zc0, s, 64);
    }
    if (lane == 0) { wr[0][wave] = (float)zc; wr[1][wave] = (float)zc0; }
    __syncthreads();
    if (tid == 0) {
        int z = 0, z0 = 0;
        #pragma unroll
        for (int j = 0; j < 16; j++) { z += (int)wr[0][j]; z0 += (int)wr[1][j]; }
        float b = floorf((0.0f - mn) / swc);    // bin of v==0 (same calc)
        b = fminf(fmaxf(b, 0.0f), 255.0f);
        hc[(int)b] += z;
        float b0 = floorf((0.0f - mn0) / sw0);
        b0 = fminf(fmaxf(b0, 0.0f), 255.0f);
        h0[(int)b0] += z0;
    }
    __syncthreads();

    // ---------------- phase C: dual scan + T LUT ----------------
    if (wave < 2) {   // wave0: channel c cdf -> scdf; wave1: channel 0 -> sc0
        const int* hsrc = wave ? h0 : hc;
        float* dst = wave ? sc0 : scdf;
        int a0 = hsrc[4*lane], a1 = hsrc[4*lane+1], a2 = hsrc[4*lane+2], a3 = hsrc[4*lane+3];
        int p1 = a0 + a1, p2 = p1 + a2, s4 = p2 + a3;
        int sc = s4;
        #pragma unroll
        for (int off = 1; off < 64; off <<= 1) {
            int t = __shfl_up(sc, off, 64);
            if (lane >= off) sc += t;
        }
        int e = sc - s4;   // exclusive prefix; counts <=16384: float exact
        *(float4*)&dst[4*lane] = make_float4((float)(e + a0), (float)(e + p1),
                                             (float)(e + p2), (float)(e + s4));
    }
    __syncthreads();
    if (tid < BINS) {   // identical math to the passing kernels
        float step = (xmx - xmn) * (1.0f / 256.0f);
        float rank = (float)(tid + 1);
        int idx = lbound(sc0, rank);
        float cp = (idx > 0) ? sc0[idx - 1] : 0.0f;
        float cu = sc0[idx];
        float ratio = fminf(fmaxf((rank - cp) / (1e-8f + cu), 0.0f), 1.0f);
        sT[tid] = xmn + (ratio + (float)idx) * step;
    }
    __syncthreads();

    // ---------------- phase D: marching inversion + SSE ----------------
    float acc = 0.0f;
    int lo = lbound(scdf, (float)(e0 + 1));   // then monotone march, ~16 reads
    #pragma unroll
    for (int i = 0; i < 16; i++) {
        float rnk = (float)(e0 + i + 1);
        while (scdf[lo] < rnk) lo++;          // scdf[255]=N bounds the march
        float d = sT[lo] - vx[i];
        acc += d * d;
    }
    #pragma unroll
    for (int s = 32; s > 0; s >>= 1) acc += __shfl_xor(acc, s, 64);
    if (lane == 0) wr[0][wave] = acc;
    __syncthreads();

    if (tid == 0) {
        float ssum = 0.0f;
        #pragma unroll
        for (int j = 0; j < 16; j++) ssum += wr[0][j];
        atomicAdd(&g_sse, ssum);
        __threadfence();
        unsigned old = atomicAdd(&g_cnt, 1u);
        if (old == (unsigned)(C_CH - 1)) {    // last block: all sse adds visible
            float sse = atomicAdd(&g_sse, 0.0f);   // coherent read
            double mean = (double)sse / (double)(C_CH * HW);
            out[0] = (float)(mean * (double)ms * (double)C_CH / (double)(C_CH * HW));
            atomicExch(&g_sse, 0.0f);   // reset for next stream-serialized replay
            atomicExch(&g_cnt, 0u);
        }
    }
}

extern "C" void kernel_launch(void* const* d_in, const int* in_sizes, int n_in,
                              void* d_out, int out_size, void* d_ws, size_t ws_size,
                              hipStream_t stream) {
    const float* input = (const float*)d_in[0];
    const float* match = (const float*)d_in[1];
    const float* mask  = (const float*)d_in[2];
    float* out         = (float*)d_out;
    (void)d_ws; (void)ws_size;

    fused_one<<<C_CH, 1024, 0, stream>>>(input, match, mask, out);
}

// Round 5
// 82.983 us; speedup vs baseline: 1.0124x; 1.0124x over previous
//
#include <hip/hip_runtime.h>
#include <math.h>

// Problem constants (fixed by setup_inputs): C=64, HW=128*128, bins=256.
#define C_CH  64
#define HW    16384
#define BINS  256

// Cross-block reduce state: module-static device globals, zero-initialized at
// module load. Self-resetting: the last (ticket) block restores both to 0
// after writing out[0], so every stream-serialized replay starts clean.
// (Pattern harness-verified in round 4.)
__device__ float    g_sse = 0.0f;
__device__ unsigned g_cnt = 0u;

__device__ inline float4 ld4(const float* p) { return *(const float4*)p; }

// Non-temporal float4 load: no-allocate at TCC. Used ONLY for the two streams
// read exactly once chip-wide (match_c, input_c) — under the post-fill L3
// writeback drain, skipping the allocate-evict step keeps reads off the
// dirty-writeback critical path. Reused data (mask, ch0) stays cached.
typedef float __attribute__((ext_vector_type(4))) f4v;
__device__ inline float4 ldnt4(const float* p) {
    f4v v = __builtin_nontemporal_load((const f4v*)p);
    return make_float4(v.x, v.y, v.z, v.w);
}

__device__ inline int lbound(const float* a, float rank) {
    int lo = 0, hi = BINS;
    while (lo < hi) { int mid = (lo + hi) >> 1; if (a[mid] < rank) lo = mid + 1; else hi = mid; }
    return (lo > 255) ? 255 : lo;   // defensive; a[255]=N>=rank
}

// ONE kernel, 64 blocks x 1024 threads: block = channel. Every block
// redundantly derives channel 0's histogram/stats (cached, L2-hot re-reads)
// instead of any cross-block communication. Phases:
//  A) coalesced loads (lane-contiguous, 16B stride): match_c/input_c via NT
//     into regs; mask/match0/input0 cached inline (min/max/sum only).
//  B) hist_c from regs; hist_0 from L2-hot match0 re-read. Zero-trick both.
//  C) dual wave scan -> cdf_c, cdf_0; T LUT from cdf_0 + ch0 input stats.
//  D) per-chunk lbound + short march CDF inversion from vx regs.
//  E) SSE wave/block reduce -> global atomic, ticket finale.
__global__ __launch_bounds__(1024, 1) void fused_one(const float* __restrict__ input,
                                                     const float* __restrict__ match,
                                                     const float* __restrict__ mask,
                                                     float* __restrict__ out) {
    const int c = blockIdx.x, tid = threadIdx.x;
    const int wave = tid >> 6, lane = tid & 63;

    __shared__ int   hc[BINS], h0[BINS];
    __shared__ float scdf[BINS], sc0[BINS], sT[BINS];
    __shared__ float wr[7][16];

    const float* mc = match + c * HW;
    const float* xc = input + c * HW;

    float vm[16], vx[16];
    float mn = INFINITY,  mx = -INFINITY;    // match_c * mask
    float mn0 = INFINITY, mx0 = -INFINITY;   // match_0 * mask
    float xmn = INFINITY, xmx = -INFINITY;   // input_0 * mask (T-LUT stats)
    float ms = 0.0f;                         // mask sum (0/1 values: exact)

    // ---------------- phase A: coalesced loads, once ----------------
    #pragma unroll
    for (int k = 0; k < 4; k++) {
        const int off = k * 4096 + 4 * tid;          // 16B lane stride: coalesced
        float4 kv = ld4(mask + off);                 // cached (reused by all blocks)
        float4 mv = ldnt4(mc + off);                 // NT: single-use stream
        float4 xv = ldnt4(xc + off);                 // NT: single-use stream
        float4 b4 = ld4(match + off);                // cached: ch0 (redundant reuse)
        float4 d4 = ld4(input + off);                // cached: ch0 (redundant reuse)
        float kk[4] = { kv.x, kv.y, kv.z, kv.w };
        float aa[4] = { mv.x, mv.y, mv.z, mv.w };
        float cc[4] = { xv.x, xv.y, xv.z, xv.w };
        float bb[4] = { b4.x, b4.y, b4.z, b4.w };
        float dd[4] = { d4.x, d4.y, d4.z, d4.w };
        #pragma unroll
        for (int j = 0; j < 4; j++) {
            float pm  = aa[j] * kk[j];
            float px  = cc[j] * kk[j];
            float pm0 = bb[j] * kk[j];
            float p0  = dd[j] * kk[j];
            vm[4*k+j] = pm;
            vx[4*k+j] = px;
            mn  = fminf(mn,  pm);  mx  = fmaxf(mx,  pm);
            mn0 = fminf(mn0, pm0); mx0 = fmaxf(mx0, pm0);
            xmn = fminf(xmn, p0);  xmx = fmaxf(xmx, p0);
            ms += kk[j];
        }
    }
    #pragma unroll
    for (int s = 32; s > 0; s >>= 1) {
        mn  = fminf(mn,  __shfl_xor(mn,  s, 64));
        mx  = fmaxf(mx,  __shfl_xor(mx,  s, 64));
        mn0 = fminf(mn0, __shfl_xor(mn0, s, 64));
        mx0 = fmaxf(mx0, __shfl_xor(mx0, s, 64));
        xmn = fminf(xmn, __shfl_xor(xmn, s, 64));
        xmx = fmaxf(xmx, __shfl_xor(xmx, s, 64));
        ms += __shfl_xor(ms, s, 64);
    }
    if (lane == 0) {
        wr[0][wave] = mn;  wr[1][wave] = mx;
        wr[2][wave] = mn0; wr[3][wave] = mx0;
        wr[4][wave] = xmn; wr[5][wave] = xmx;
        wr[6][wave] = ms;
    }
    if (tid < BINS) { hc[tid] = 0; h0[tid] = 0; }
    __syncthreads();
    mn = wr[0][0]; mx = wr[1][0]; mn0 = wr[2][0]; mx0 = wr[3][0];
    xmn = wr[4][0]; xmx = wr[5][0]; ms = wr[6][0];
    #pragma unroll
    for (int j = 1; j < 16; j++) {
        mn  = fminf(mn,  wr[0][j]); mx  = fmaxf(mx,  wr[1][j]);
        mn0 = fminf(mn0, wr[2][j]); mx0 = fmaxf(mx0, wr[3][j]);
        xmn = fminf(xmn, wr[4][j]); xmx = fmaxf(xmx, wr[5][j]);
        ms += wr[6][j];
    }

    // torch.histc widths: w=(mx-mn)/bins; safe_w = w>0 ? w : 1  (/256 exact)
    float swc = (mx  - mn ) * (1.0f / 256.0f); swc = (swc > 0.0f) ? swc : 1.0f;
    float sw0 = (mx0 - mn0) * (1.0f / 256.0f); sw0 = (sw0 > 0.0f) ? sw0 : 1.0f;

    // ---------------- phase B: hist_c from regs; hist_0 from L2-hot re-read --
    int zc = 0, zc0 = 0;   // exact zeros (incl -0): counted without atomics
    #pragma unroll
    for (int j = 0; j < 16; j++) {
        if (vm[j] == 0.0f) { zc++; }
        else {
            float b = floorf((vm[j] - mn) / swc);
            b = fminf(fmaxf(b, 0.0f), 255.0f);   // clip in float like the ref
            atomicAdd(&hc[(int)b], 1);
        }
    }
    #pragma unroll
    for (int k = 0; k < 4; k++) {
        const int off = k * 4096 + 4 * tid;
        float4 kv = ld4(mask + off);             // L1/L2-hot
        float4 b4 = ld4(match + off);            // L1/L2-hot ch0
        float v0[4] = { b4.x * kv.x, b4.y * kv.y, b4.z * kv.z, b4.w * kv.w };
        #pragma unroll
        for (int j = 0; j < 4; j++) {
            if (v0[j] == 0.0f) { zc0++; }        // identical recompute: same bits
            else {
                float b = floorf((v0[j] - mn0) / sw0);
                b = fminf(fmaxf(b, 0.0f), 255.0f);
                atomicAdd(&h0[(int)b], 1);
            }
        }
    }
    #pragma unroll
    for (int s = 32; s > 0; s >>= 1) {
        zc  += __shfl_xor(zc,  s, 64);
        zc0 += __shfl_xor(zc0, s, 64);
    }
    if (lane == 0) { wr[0][wave] = (float)zc; wr[1][wave] = (float)zc0; }
    __syncthreads();
    if (tid == 0) {
        int z = 0, z0 = 0;
        #pragma unroll
        for (int j = 0; j < 16; j++) { z += (int)wr[0][j]; z0 += (int)wr[1][j]; }
        float b = floorf((0.0f - mn) / swc);    // bin of v==0 (same calc)
        b = fminf(fmaxf(b, 0.0f), 255.0f);
        hc[(int)b] += z;
        float b0 = floorf((0.0f - mn0) / sw0);
        b0 = fminf(fmaxf(b0, 0.0f), 255.0f);
        h0[(int)b0] += z0;
    }
    __syncthreads();

    // ---------------- phase C: dual scan + T LUT ----------------
    if (wave < 2) {   // wave0: channel c cdf -> scdf; wave1: channel 0 -> sc0
        const int* hsrc = wave ? h0 : hc;
        float* dst = wave ? sc0 : scdf;
        int a0 = hsrc[4*lane], a1 = hsrc[4*lane+1], a2 = hsrc[4*lane+2], a3 = hsrc[4*lane+3];
        int p1 = a0 + a1, p2 = p1 + a2, s4 = p2 + a3;
        int sc = s4;
        #pragma unroll
        for (int off = 1; off < 64; off <<= 1) {
            int t = __shfl_up(sc, off, 64);
            if (lane >= off) sc += t;
        }
        int e = sc - s4;   // exclusive prefix; counts <=16384: float exact
        *(float4*)&dst[4*lane] = make_float4((float)(e + a0), (float)(e + p1),
                                             (float)(e + p2), (float)(e + s4));
    }
    __syncthreads();
    if (tid < BINS) {   // identical math to the passing kernels
        float step = (xmx - xmn) * (1.0f / 256.0f);
        float rank = (float)(tid + 1);
        int idx = lbound(sc0, rank);
        float cp = (idx > 0) ? sc0[idx - 1] : 0.0f;
        float cu = sc0[idx];
        float ratio = fminf(fmaxf((rank - cp) / (1e-8f + cu), 0.0f), 1.0f);
        sT[tid] = xmn + (ratio + (float)idx) * step;
    }
    __syncthreads();

    // ---------------- phase D: per-chunk lbound + short march ----------------
    float acc = 0.0f;
    #pragma unroll
    for (int k = 0; k < 4; k++) {
        const int idx0 = k * 4096 + 4 * tid;
        int lo = lbound(scdf, (float)(idx0 + 1));   // 8 reads; then <=3 marches
        #pragma unroll
        for (int j = 0; j < 4; j++) {
            float rnk = (float)(idx0 + j + 1);
            while (scdf[lo] < rnk) lo++;            // scdf[255]=N bounds the march
            float d = sT[lo] - vx[4*k+j];
            acc += d * d;
        }
    }
    #pragma unroll
    for (int s = 32; s > 0; s >>= 1) acc += __shfl_xor(acc, s, 64);
    if (lane == 0) wr[0][wave] = acc;
    __syncthreads();

    if (tid == 0) {
        float ssum = 0.0f;
        #pragma unroll
        for (int j = 0; j < 16; j++) ssum += wr[0][j];
        atomicAdd(&g_sse, ssum);
        __threadfence();
        unsigned old = atomicAdd(&g_cnt, 1u);
        if (old == (unsigned)(C_CH - 1)) {    // last block: all sse adds visible
            float sse = atomicAdd(&g_sse, 0.0f);   // coherent read
            double mean = (double)sse / (double)(C_CH * HW);
            out[0] = (float)(mean * (double)ms * (double)C_CH / (double)(C_CH * HW));
            atomicExch(&g_sse, 0.0f);   // reset for next stream-serialized replay
            atomicExch(&g_cnt, 0u);
        }
    }
}

extern "C" void kernel_launch(void* const* d_in, const int* in_sizes, int n_in,
                              void* d_out, int out_size, void* d_ws, size_t ws_size,
                              hipStream_t stream) {
    const float* input = (const float*)d_in[0];
    const float* match = (const float*)d_in[1];
    const float* mask  = (const float*)d_in[2];
    float* out         = (float*)d_out;
    (void)d_ws; (void)ws_size;

    fused_one<<<C_CH, 1024, 0, stream>>>(input, match, mask, out);
}

// Round 6
// 78.442 us; speedup vs baseline: 1.0710x; 1.0579x over previous
//
#include <hip/hip_runtime.h>
#include <math.h>

// Problem constants (fixed by setup_inputs): C=64 channels, HW=128*128, bins=256.
#define C_CH  64
#define HW    16384
#define BINS  256

// ---- ws layout (32-bit cells; everything written before read -> no memset) ----
#define WS_CDF   0                    // 64*256 floats: per-channel inclusive cdf
#define WS_XMN   (C_CH * BINS)       // ch0 input*mask min
#define WS_XMX   (WS_XMN + 1)        // ch0 input*mask max
#define WS_MSUM  (WS_XMN + 2)        // mask sum
#define WS_SSE   (WS_XMN + 3)        // float SSE accumulator (zeroed by K1 blk 64)
#define WS_CNT   (WS_XMN + 4)        // int ticket counter   (zeroed by K1 blk 64)

__device__ inline float4 ld4(const float* p) { return *(const float4*)p; }

__device__ inline int lbound(const float* a, float rank) {
    int lo = 0, hi = BINS;
    while (lo < hi) { int mid = (lo + hi) >> 1; if (a[mid] < rank) lo = mid + 1; else hi = mid; }
    return (lo > 255) ? 255 : lo;   // cannot trigger (a[255]=N>=rank); defensive
}

// K1: blocks 0..63 = one channel each. Single global pass: load 16 elems/thread
// into registers, wave-shuffle min/max, LDS histogram from registers (exact
// zeros counted separately — ~30% of values are masked-out zeros that would
// serialize same-address LDS atomics), wave-0 shuffle scan -> cdf.
// Block 64: ch0 input*mask min/max + mask sum + zero sse/ticket cells.
// Only ~4 __syncthreads per block (vs ~40 in the tree-reduction version).
__global__ __launch_bounds__(1024, 4) void k1_hist(const float* __restrict__ input,
                                                   const float* __restrict__ match,
                                                   const float* __restrict__ mask,
                                                   float* __restrict__ ws) {
    const int b = blockIdx.x, tid = threadIdx.x;
    const int wave = tid >> 6, lane = tid & 63;
    __shared__ float wmin[16], wmax[16], wsum[16];
    __shared__ int hist[BINS];

    if (b < C_CH) {
        const float* m = match + b * HW;

        // single pass: load+mask into registers, track min/max
        float v[16];
        float mn = INFINITY, mx = -INFINITY;
        #pragma unroll
        for (int k = 0; k < 4; k++) {
            float4 mv = ld4(m + k * 4096 + 4 * tid);
            float4 kv = ld4(mask + k * 4096 + 4 * tid);
            v[4 * k + 0] = mv.x * kv.x; v[4 * k + 1] = mv.y * kv.y;
            v[4 * k + 2] = mv.z * kv.z; v[4 * k + 3] = mv.w * kv.w;
            #pragma unroll
            for (int j = 0; j < 4; j++) {
                mn = fminf(mn, v[4 * k + j]);
                mx = fmaxf(mx, v[4 * k + j]);
            }
        }
        // wave-level reduce (no barriers), then cross-wave via LDS (1 barrier)
        #pragma unroll
        for (int s = 32; s > 0; s >>= 1) {
            mn = fminf(mn, __shfl_xor(mn, s, 64));
            mx = fmaxf(mx, __shfl_xor(mx, s, 64));
        }
        if (lane == 0) { wmin[wave] = mn; wmax[wave] = mx; }
        if (tid < BINS) hist[tid] = 0;
        __syncthreads();
        mn = wmin[0]; mx = wmax[0];
        #pragma unroll
        for (int j = 1; j < 16; j++) { mn = fminf(mn, wmin[j]); mx = fmaxf(mx, wmax[j]); }

        // torch.histc: w = (mx-mn)/bins; safe_w = w>0 ? w : 1   (/256 exact)
        float w  = (mx - mn) * (1.0f / 256.0f);
        float sw = (w > 0.0f) ? w : 1.0f;

        // histogram from registers; exact zeros (incl -0) counted without atomics
        int zc = 0;
        #pragma unroll
        for (int j = 0; j < 16; j++) {
            if (v[j] == 0.0f) { zc++; }
            else {
                float bb = floorf((v[j] - mn) / sw);
                bb = fminf(fmaxf(bb, 0.0f), 255.0f);   // clip in float like the ref
                atomicAdd(&hist[(int)bb], 1);
            }
        }
        // reduce zero-count: wave shuffle + LDS fold
        #pragma unroll
        for (int s = 32; s > 0; s >>= 1) zc += __shfl_xor(zc, s, 64);
        if (lane == 0) wsum[wave] = (float)zc;
        __syncthreads();
        if (tid == 0) {
            int z = 0;
            #pragma unroll
            for (int j = 0; j < 16; j++) z += (int)wsum[j];
            float bb = floorf((0.0f - mn) / sw);       // bin of v==0 (same calc as per-elem)
            bb = fminf(fmaxf(bb, 0.0f), 255.0f);
            hist[(int)bb] += z;
        }
        __syncthreads();

        // wave 0: 256-bin inclusive scan, 4 bins/lane, shuffle prefix — no barriers
        if (wave == 0) {
            int h0 = hist[4 * lane], h1 = hist[4 * lane + 1];
            int h2 = hist[4 * lane + 2], h3 = hist[4 * lane + 3];
            int p1 = h0 + h1, p2 = p1 + h2, s4 = p2 + h3;
            int sc = s4;
            #pragma unroll
            for (int off = 1; off < 64; off <<= 1) {
                int t = __shfl_up(sc, off, 64);
                if (lane >= off) sc += t;
            }
            int e = sc - s4;   // exclusive prefix
            float4 o = make_float4((float)(e + h0), (float)(e + p1),
                                   (float)(e + p2), (float)(e + s4));  // ints<=16384: exact
            *(float4*)&ws[WS_CDF + b * BINS + 4 * lane] = o;
        }
    } else {
        // block 64: ch0 x=input*mask min/max, mask sum, zero accumulators
        float xmn = INFINITY, xmx = -INFINITY, msum = 0.0f;
        #pragma unroll
        for (int k = 0; k < 4; k++) {
            float4 xv = ld4(input + k * 4096 + 4 * tid);
            float4 kv = ld4(mask + k * 4096 + 4 * tid);
            float v0 = xv.x * kv.x, v1 = xv.y * kv.y, v2 = xv.z * kv.z, v3 = xv.w * kv.w;
            xmn = fminf(xmn, fminf(fminf(v0, v1), fminf(v2, v3)));
            xmx = fmaxf(xmx, fmaxf(fmaxf(v0, v1), fmaxf(v2, v3)));
            msum += kv.x + kv.y + kv.z + kv.w;   // 0/1 values: exact
        }
        #pragma unroll
        for (int s = 32; s > 0; s >>= 1) {
            xmn = fminf(xmn, __shfl_xor(xmn, s, 64));
            xmx = fmaxf(xmx, __shfl_xor(xmx, s, 64));
            msum += __shfl_xor(msum, s, 64);
        }
        if (lane == 0) { wmin[wave] = xmn; wmax[wave] = xmx; wsum[wave] = msum; }
        __syncthreads();
        if (tid == 0) {
            #pragma unroll
            for (int j = 1; j < 16; j++) {
                xmn = fminf(xmn, wmin[j]);
                xmx = fmaxf(xmx, wmax[j]);
            }
            float ms = 0.0f;
            #pragma unroll
            for (int j = 0; j < 16; j++) ms += wsum[j];
            ws[WS_XMN] = xmn;
            ws[WS_XMX] = xmx;
            ws[WS_MSUM] = ms;
            ws[WS_SSE] = 0.0f;
            ((int*)ws)[WS_CNT] = 0;
        }
    }
}

// K2: 256 blocks x 256 threads, each block = 4096 contiguous elements of one
// channel (4 blocks/channel). Rebuilds the T LUT locally from cdf0 + ch0 stats,
// marching-pointer CDF inversion, block reduce -> atomicAdd(sse) (256 total
// same-address atomics, not 1024). Ticket finale writes out[0].
__global__ __launch_bounds__(256) void k2_loss(const float* __restrict__ input,
                                               const float* __restrict__ mask,
                                               float* __restrict__ ws,
                                               float* __restrict__ out) {
    const int c = blockIdx.x >> 2;
    const int base = (blockIdx.x & 3) * 4096;
    const int tid = threadIdx.x;
    const int wave = tid >> 6, lane = tid & 63;

    __shared__ float scdf[BINS], sc0[BINS], sT[BINS], red[4];
    scdf[tid] = ws[WS_CDF + c * BINS + tid];
    sc0[tid]  = ws[WS_CDF + tid];
    __syncthreads();

    // T[j] from channel-0 stats: idx = count(cdf0 < j+1) == lower_bound (monotone)
    {
        const float xmn = ws[WS_XMN], xmx = ws[WS_XMX];
        float step = (xmx - xmn) * (1.0f / 256.0f);
        float rank = (float)(tid + 1);
        int idx = lbound(sc0, rank);
        float cp = (idx > 0) ? sc0[idx - 1] : 0.0f;
        float cc = sc0[idx];
        float ratio = fminf(fmaxf((rank - cp) / (1e-8f + cc), 0.0f), 1.0f);
        sT[tid] = xmn + (ratio + (float)idx) * step;
    }
    __syncthreads();

    const float* x  = input + c * HW + base;
    const float* mk = mask + base;

    float acc = 0.0f;
    // first rank of this thread's first chunk: binary search; then monotone march
    int lo = lbound(scdf, (float)(base + 4 * tid + 1));
    #pragma unroll
    for (int k = 0; k < 4; k++) {
        float4 xv = ld4(x + k * 1024 + 4 * tid);
        float4 kv = ld4(mk + k * 1024 + 4 * tid);
        float v[4] = { xv.x * kv.x, xv.y * kv.y, xv.z * kv.z, xv.w * kv.w };
        float rank0 = (float)(base + k * 1024 + 4 * tid + 1);
        #pragma unroll
        for (int j = 0; j < 4; j++) {
            float rnk = rank0 + (float)j;
            while (scdf[lo] < rnk) lo++;   // scdf[255] = N bounds the march
            float d = sT[lo] - v[j];
            acc += d * d;
        }
    }

    // block reduce: wave shuffle + tiny LDS fold
    #pragma unroll
    for (int s = 32; s > 0; s >>= 1) acc += __shfl_xor(acc, s, 64);
    if (lane == 0) red[wave] = acc;
    __syncthreads();

    if (tid == 0) {
        float ssum = red[0] + red[1] + red[2] + red[3];
        atomicAdd(&ws[WS_SSE], ssum);
        __threadfence();
        int old = atomicAdd(&((int*)ws)[WS_CNT], 1);
        if (old == gridDim.x - 1) {             // last block: all sse adds visible
            float sse  = atomicAdd(&ws[WS_SSE], 0.0f);   // coherent read
            float msum = ws[WS_MSUM];
            double mean = (double)sse / (double)(C_CH * HW);
            out[0] = (float)(mean * (double)msum * (double)C_CH / (double)(C_CH * HW));
        }
    }
}

extern "C" void kernel_launch(void* const* d_in, const int* in_sizes, int n_in,
                              void* d_out, int out_size, void* d_ws, size_t ws_size,
                              hipStream_t stream) {
    const float* input = (const float*)d_in[0];
    const float* match = (const float*)d_in[1];
    const float* mask  = (const float*)d_in[2];
    float* ws          = (float*)d_ws;
    float* out         = (float*)d_out;

    k1_hist<<<C_CH + 1, 1024, 0, stream>>>(input, match, mask, ws);
    k2_loss<<<C_CH * 4, 256,  0, stream>>>(input, mask, ws, out);
}